// Round 1
// baseline (39.610 us; speedup 1.0000x reference)
//
#include <hip/hip_runtime.h>

#define NPROTO 20
#define SEQ_LEN 512

// One block per batch row; thread l computes output position l.
// Bit-exactness notes (output is binary -> any f32 sign flip vs JAX ref fails):
//  - same associativity as the reference expressions (no reassociation; there
//    are no mul+add adjacencies, so ffp-contract cannot introduce fma on
//    either side)
//  - IEEE f32 divides kept as divides (base/3.0f, q*(m-512)/denom, sum/20)
//  - rintf == jnp.round (round half to even)
//  - sequential p=0..19 summation order, matching XLA's sequential loop over
//    the size-20 reduced (non-minor) axis
__global__ __launch_bounds__(512)
void adaptive_mask_kernel(const float* __restrict__ tok,
                          const float* __restrict__ sigma,
                          const float* __restrict__ pi,
                          float* __restrict__ out)
{
    const int b = blockIdx.x;
    const int l = threadIdx.x;

    __shared__ float4 s_par[NPROTO];   // {m, aL, aR, den}
    __shared__ float  s_pi[NPROTO];
    __shared__ unsigned s_kmask;

    if (l < NPROTO) {
        const int idx = b * NPROTO + l;
        const float t  = tok[idx];
        const float sg = sigma[idx];
        // m = round(clip(t, 1, 511)), round-half-even like jnp.round
        const float m  = rintf(fminf(fmaxf(t, 1.0f), 511.0f));
        const float aL = (0.001f * sg) * m;             // CVL*sigma*m (left-assoc)
        const float aR = (0.001f * sg) * (512.0f - m);  // CVR*sigma*(MAX_LEN-m)
        const float den = (m == 511.0f) ? 1.0f : (511.0f - m);
        s_par[l] = make_float4(m, aL, aR, den);
        s_pi[l]  = pi[idx];
    }
    __syncthreads();

    if (l == 0) {
        // mean over the 20 pi values, sequential order, then keep bitmask
        float s = 0.0f;
        for (int p = 0; p < NPROTO; ++p) s += s_pi[p];
        const float mean = s / 20.0f;
        unsigned km = 0;
        for (int p = 0; p < NPROTO; ++p)
            if (s_pi[p] >= mean) km |= (1u << p);
        s_kmask = km;
    }
    __syncthreads();

    // scalarize the keep mask so the skip branch is wave-uniform (s_cbranch)
    unsigned km = __builtin_amdgcn_readfirstlane(s_kmask);

    const float lf = (float)l;
    float acc = 0.0f;
    #pragma unroll 1
    for (int p = 0; p < NPROTO; ++p) {
        if (!((km >> p) & 1u)) continue;   // dropped prototype contributes exact 0
        const float4 pr = s_par[p];
        const float m = pr.x;
        float base;
        if (lf < m) {
            // left = (p - m + 1.0) + CVL*sigma*m
            base = ((lf - m) + 1.0f) + pr.y;
        } else {
            // right = (-1.0 + q*(m-512)/denom) + CVR*sigma*(512-m)
            const float q = lf - m;
            base = (-1.0f + (q * (m - 512.0f)) / pr.w) + pr.z;
        }
        const float val = base / 3.0f + 1.0f;   // base/RAMP + 1
        acc += val;
    }

    // summed=clip(acc,0,1); mask = summed>0 ? 1:0  ==  acc>0 ? 1:0
    out[(size_t)b * SEQ_LEN + l] = (acc > 0.0f) ? 1.0f : 0.0f;
}

extern "C" void kernel_launch(void* const* d_in, const int* in_sizes, int n_in,
                              void* d_out, int out_size, void* d_ws, size_t ws_size,
                              hipStream_t stream)
{
    const float* tok   = (const float*)d_in[0];
    const float* sigma = (const float*)d_in[1];
    const float* pi    = (const float*)d_in[2];
    float* out = (float*)d_out;

    const int B = in_sizes[0] / NPROTO;   // 8192
    adaptive_mask_kernel<<<B, 512, 0, stream>>>(tok, sigma, pi, out);
}

// Round 2
// 37.139 us; speedup vs baseline: 1.0665x; 1.0665x over previous
//
#include <hip/hip_runtime.h>

#define NPROTO 20
#define SEQ_LEN 512

// ---------------------------------------------------------------------------
// R-table: R[m*512 + l] = ((l - m) * (m - 512)) / ((m==511) ? 1 : (511 - m))
// Both (l-m) and (m-512) are exact small integers in f32; their product is
// < 2^18 so exact; the f32 divide is the SAME correctly-rounded operation the
// reference performs elementwise -> table values are bit-identical.
// ---------------------------------------------------------------------------
__global__ __launch_bounds__(256)
void build_rtable(float* __restrict__ R)
{
    const int idx = blockIdx.x * 256 + threadIdx.x;   // 0 .. 262143
    const int m = idx >> 9;
    const int l = idx & 511;
    const float mf = (float)m;
    const float num = ((float)l - mf) * (mf - 512.0f);   // exact
    const float den = (m == 511) ? 1.0f : (511.0f - mf);
    R[idx] = num / den;
}

// ---------------------------------------------------------------------------
// Main kernel: one block per batch row, 256 threads, 2 positions per thread
// (l = t and t+256) for ILP on the div-by-3 latency chain.
// Bit-exactness: identical op order/associativity to the JAX reference; the
// only divides left are base/3.0f (IEEE). Right-side divide comes from the
// bit-identical R table. Dropped prototypes contribute exact 0 (skipped).
// ---------------------------------------------------------------------------
__global__ __launch_bounds__(256)
void adaptive_mask_kernel(const float* __restrict__ tok,
                          const float* __restrict__ sigma,
                          const float* __restrict__ pi,
                          const float* __restrict__ R,
                          float* __restrict__ out)
{
    const int b = blockIdx.x;
    const int t = threadIdx.x;

    __shared__ float4 s_par[NPROTO];   // {m, aL, aR, unused}
    __shared__ float  s_pi[NPROTO];
    __shared__ unsigned s_kmask;

    if (t < NPROTO) {
        const int idx = b * NPROTO + t;
        const float tk = tok[idx];
        const float sg = sigma[idx];
        const float m  = rintf(fminf(fmaxf(tk, 1.0f), 511.0f)); // round-half-even
        const float aL = (0.001f * sg) * m;                     // CVL*sigma*m
        const float aR = (0.001f * sg) * (512.0f - m);          // CVR*sigma*(512-m)
        s_par[t] = make_float4(m, aL, aR, 0.0f);
        s_pi[t]  = pi[idx];
    }
    __syncthreads();

    if (t == 0) {
        float s = 0.0f;
        for (int p = 0; p < NPROTO; ++p) s += s_pi[p];   // sequential, like XLA
        const float mean = s / 20.0f;
        unsigned kmv = 0;
        for (int p = 0; p < NPROTO; ++p)
            if (s_pi[p] >= mean) kmv |= (1u << p);
        s_kmask = kmv;
    }
    __syncthreads();

    const unsigned km = __builtin_amdgcn_readfirstlane(s_kmask);

    const float lf0 = (float)t;
    const float lf1 = (float)(t + 256);
    float acc0 = 0.0f, acc1 = 0.0f;

    #pragma unroll 1
    for (int p = 0; p < NPROTO; ++p) {
        if (!((km >> p) & 1u)) continue;    // exact-0 contribution, skip
        const float4 pr = s_par[p];
        const float m  = pr.x;
        const int rowbase = ((int)m) << 9;

        const float rv0 = R[rowbase + t];
        const float rv1 = R[rowbase + t + 256];

        // left  = ((l - m) + 1) + aL
        // right = (-1 + R[m][l]) + aR
        const float bl0 = ((lf0 - m) + 1.0f) + pr.y;
        const float br0 = (-1.0f + rv0) + pr.z;
        const float base0 = (lf0 < m) ? bl0 : br0;
        const float v0 = base0 / 3.0f + 1.0f;
        acc0 += v0;

        const float bl1 = ((lf1 - m) + 1.0f) + pr.y;
        const float br1 = (-1.0f + rv1) + pr.z;
        const float base1 = (lf1 < m) ? bl1 : br1;
        const float v1 = base1 / 3.0f + 1.0f;
        acc1 += v1;
    }

    const size_t o = (size_t)b * SEQ_LEN + t;
    out[o]       = (acc0 > 0.0f) ? 1.0f : 0.0f;
    out[o + 256] = (acc1 > 0.0f) ? 1.0f : 0.0f;
}

// ---------------------------------------------------------------------------
// Fallback (ws too small): the R1 kernel, exact with inline divides.
// ---------------------------------------------------------------------------
__global__ __launch_bounds__(512)
void adaptive_mask_kernel_nolut(const float* __restrict__ tok,
                                const float* __restrict__ sigma,
                                const float* __restrict__ pi,
                                float* __restrict__ out)
{
    const int b = blockIdx.x;
    const int l = threadIdx.x;

    __shared__ float4 s_par[NPROTO];
    __shared__ float  s_pi[NPROTO];
    __shared__ unsigned s_kmask;

    if (l < NPROTO) {
        const int idx = b * NPROTO + l;
        const float tk = tok[idx];
        const float sg = sigma[idx];
        const float m  = rintf(fminf(fmaxf(tk, 1.0f), 511.0f));
        const float aL = (0.001f * sg) * m;
        const float aR = (0.001f * sg) * (512.0f - m);
        const float den = (m == 511.0f) ? 1.0f : (511.0f - m);
        s_par[l] = make_float4(m, aL, aR, den);
        s_pi[l]  = pi[idx];
    }
    __syncthreads();

    if (l == 0) {
        float s = 0.0f;
        for (int p = 0; p < NPROTO; ++p) s += s_pi[p];
        const float mean = s / 20.0f;
        unsigned kmv = 0;
        for (int p = 0; p < NPROTO; ++p)
            if (s_pi[p] >= mean) kmv |= (1u << p);
        s_kmask = kmv;
    }
    __syncthreads();

    const unsigned km = __builtin_amdgcn_readfirstlane(s_kmask);

    const float lf = (float)l;
    float acc = 0.0f;
    #pragma unroll 1
    for (int p = 0; p < NPROTO; ++p) {
        if (!((km >> p) & 1u)) continue;
        const float4 pr = s_par[p];
        const float m = pr.x;
        float base;
        if (lf < m) {
            base = ((lf - m) + 1.0f) + pr.y;
        } else {
            const float q = lf - m;
            base = (-1.0f + (q * (m - 512.0f)) / pr.w) + pr.z;
        }
        acc += base / 3.0f + 1.0f;
    }
    out[(size_t)b * SEQ_LEN + l] = (acc > 0.0f) ? 1.0f : 0.0f;
}

extern "C" void kernel_launch(void* const* d_in, const int* in_sizes, int n_in,
                              void* d_out, int out_size, void* d_ws, size_t ws_size,
                              hipStream_t stream)
{
    const float* tok   = (const float*)d_in[0];
    const float* sigma = (const float*)d_in[1];
    const float* pi    = (const float*)d_in[2];
    float* out = (float*)d_out;
    const int B = in_sizes[0] / NPROTO;   // 8192

    const size_t tab_bytes = 512 * 512 * sizeof(float);   // 1 MiB
    if (ws_size >= tab_bytes) {
        float* R = (float*)d_ws;
        build_rtable<<<512 * 512 / 256, 256, 0, stream>>>(R);
        adaptive_mask_kernel<<<B, 256, 0, stream>>>(tok, sigma, pi, R, out);
    } else {
        adaptive_mask_kernel_nolut<<<B, 512, 0, stream>>>(tok, sigma, pi, out);
    }
}

// Round 3
// 21.354 us; speedup vs baseline: 1.8549x; 1.7392x over previous
//
#include <hip/hip_runtime.h>

#define NPROTO 20
#define SEQ_LEN 512

// Correctly-rounded a/d via Markstein refinement, given rc = RN(1/d).
// Exactness (vs IEEE divide) for THIS kernel's operand sets:
//  - d = 3.0f (rc = RN(1/3), compile-time 1.0f/3.0f): a/3 is either exact
//    (3 | mantissa) or non-terminating (never a rounding tie); boundary gap
//    >= ulp/6 >> refined error (~2^-24 ulp). Correct for all f32 a.
//  - d = integer denom in [1,510], a = num = exact integer product < 2^18:
//    num/d is exact or non-terminating; boundary gap >= ~ulp/2^10 >> error.
// So q1 == RN(a/d) bit-exactly, replacing the ~12-instr IEEE div sequence
// with 1 mul + 2 fma.
__device__ __forceinline__ float div_exact(float a, float d, float rc)
{
    const float q0 = a * rc;
    const float r  = fmaf(-d, q0, a);
    return fmaf(r, rc, q0);
}

// One block per batch row, 256 threads, 2 positions per thread (l = t, t+256).
// Inner loop is pure VALU (no global/table loads): per-prototype params are
// broadcast from LDS. All f32 ops replicate the reference's exact order and
// associativity; the only IEEE divides left run in the 20-lane setup phase.
__global__ __launch_bounds__(256)
void adaptive_mask_kernel(const float* __restrict__ tok,
                          const float* __restrict__ sigma,
                          const float* __restrict__ pi,
                          float* __restrict__ out)
{
    const int b = blockIdx.x;
    const int t = threadIdx.x;

    __shared__ float4 s_p4[NPROTO];   // {m, aL, aR, rc=RN(1/den)}
    __shared__ float2 s_p2[NPROTO];   // {msub=m-512, den}
    __shared__ float  s_pi[NPROTO];
    __shared__ unsigned s_kmask;

    if (t < NPROTO) {
        const int idx = b * NPROTO + t;
        const float tk = tok[idx];
        const float sg = sigma[idx];
        const float m  = rintf(fminf(fmaxf(tk, 1.0f), 511.0f)); // round-half-even
        const float aL = (0.001f * sg) * m;                     // CVL*sigma*m
        const float aR = (0.001f * sg) * (512.0f - m);          // CVR*sigma*(512-m)
        const float den = (m == 511.0f) ? 1.0f : (511.0f - m);
        const float rc  = 1.0f / den;                           // IEEE, RN(1/den)
        s_p4[t] = make_float4(m, aL, aR, rc);
        s_p2[t] = make_float2(m - 512.0f, den);
        s_pi[t] = pi[idx];
    }
    __syncthreads();

    if (t == 0) {
        float s = 0.0f;
        for (int p = 0; p < NPROTO; ++p) s += s_pi[p];   // sequential, like XLA
        const float mean = s / 20.0f;
        unsigned kmv = 0;
        for (int p = 0; p < NPROTO; ++p)
            if (s_pi[p] >= mean) kmv |= (1u << p);
        s_kmask = kmv;
    }
    __syncthreads();

    const unsigned km = __builtin_amdgcn_readfirstlane(s_kmask);
    const float C3 = 1.0f / 3.0f;     // RN(1/3), compile-time

    const float lf0 = (float)t;
    const float lf1 = (float)(t + 256);
    float acc0 = 0.0f, acc1 = 0.0f;

    #pragma unroll
    for (int p = 0; p < NPROTO; ++p) {
        if (!((km >> p) & 1u)) continue;   // dropped prototype == exact 0
        const float4 P = s_p4[p];
        const float2 Q = s_p2[p];
        const float m = P.x, aL = P.y, aR = P.z, rc = P.w;
        const float msub = Q.x, den = Q.y;

        {   // l = t
            const float q    = lf0 - m;
            const float num  = q * msub;                   // exact int product
            const float rq   = div_exact(num, den, rc);    // == RN(num/den)
            const float left = (q + 1.0f) + aL;            // ((l-m)+1)+aL
            const float rt   = (-1.0f + rq) + aR;          // (-1+q*(m-512)/den)+aR
            const float base = (lf0 < m) ? left : rt;
            acc0 += div_exact(base, 3.0f, C3) + 1.0f;      // base/3 + 1
        }
        {   // l = t + 256
            const float q    = lf1 - m;
            const float num  = q * msub;
            const float rq   = div_exact(num, den, rc);
            const float left = (q + 1.0f) + aL;
            const float rt   = (-1.0f + rq) + aR;
            const float base = (lf1 < m) ? left : rt;
            acc1 += div_exact(base, 3.0f, C3) + 1.0f;
        }
    }

    const size_t o = (size_t)b * SEQ_LEN + t;
    out[o]       = (acc0 > 0.0f) ? 1.0f : 0.0f;
    out[o + 256] = (acc1 > 0.0f) ? 1.0f : 0.0f;
}

extern "C" void kernel_launch(void* const* d_in, const int* in_sizes, int n_in,
                              void* d_out, int out_size, void* d_ws, size_t ws_size,
                              hipStream_t stream)
{
    const float* tok   = (const float*)d_in[0];
    const float* sigma = (const float*)d_in[1];
    const float* pi    = (const float*)d_in[2];
    float* out = (float*)d_out;

    const int B = in_sizes[0] / NPROTO;   // 8192
    adaptive_mask_kernel<<<B, 256, 0, stream>>>(tok, sigma, pi, out);
}